// Round 1
// baseline (370.250 us; speedup 1.0000x reference)
//
#include <hip/hip_runtime.h>
#include <hip/hip_bf16.h>

#define SS 2048
#define DD 2048
#define HH 16
#define HDIM 128

typedef unsigned short u16;
typedef __attribute__((ext_vector_type(8))) short bf16x8;
typedef __attribute__((ext_vector_type(4))) float f32x4;
typedef __attribute__((ext_vector_type(4))) unsigned short u16x4;

__device__ __forceinline__ u16 f2bf(float f){
  unsigned u = __float_as_uint(f);
  u += 0x7FFFu + ((u >> 16) & 1u);
  return (u16)(u >> 16);
}

__device__ __forceinline__ void gload_lds16(const void* g, void* l){
  __builtin_amdgcn_global_load_lds(
      (const __attribute__((address_space(1))) void*)g,
      (__attribute__((address_space(3))) void*)l, 16, 0, 0);
}

__device__ __forceinline__ f32x4 mfma16(bf16x8 a, bf16x8 b, f32x4 c){
  return __builtin_amdgcn_mfma_f32_16x16x32_bf16(a, b, c, 0, 0, 0);
}

// ---------------- K1: fused embedding add + LayerNorm ----------------
__global__ __launch_bounds__(256) void k_embed_ln(
    const float* __restrict__ br, const int* __restrict__ cat,
    const int* __restrict__ cse, const int* __restrict__ cmb,
    const float* __restrict__ cat_e, const float* __restrict__ case_e,
    const float* __restrict__ comb_e, const float* __restrict__ lg,
    const float* __restrict__ lb, float* __restrict__ xn32, u16* __restrict__ xn16)
{
  const int s = blockIdx.x, t = threadIdx.x;
  const int lane = t & 63, wave = t >> 6;
  const int c0 = cat[s], c1 = cse[s], c2 = cmb[s];
  const f32x4* pb = (const f32x4*)(br + (size_t)s * DD);
  const f32x4* e0 = (const f32x4*)(cat_e + (size_t)c0 * DD);
  const f32x4* e1 = (const f32x4*)(case_e + (size_t)c1 * DD);
  const f32x4* e2 = (const f32x4*)(comb_e + (size_t)c2 * DD);
  f32x4 xa = pb[t] + e0[t] + e1[t] + e2[t];
  f32x4 xb = pb[t+256] + e0[t+256] + e1[t+256] + e2[t+256];
  float s1 = 0.f, s2 = 0.f;
#pragma unroll
  for (int i = 0; i < 4; ++i){ s1 += xa[i] + xb[i]; s2 += xa[i]*xa[i] + xb[i]*xb[i]; }
#pragma unroll
  for (int off = 32; off > 0; off >>= 1){ s1 += __shfl_down(s1, off); s2 += __shfl_down(s2, off); }
  __shared__ float red[8];
  if (lane == 0){ red[wave*2] = s1; red[wave*2+1] = s2; }
  __syncthreads();
  const float t1 = red[0]+red[2]+red[4]+red[6];
  const float t2 = red[1]+red[3]+red[5]+red[7];
  const float mean = t1 * (1.0f/DD);
  const float var  = t2 * (1.0f/DD) - mean*mean;
  const float rstd = rsqrtf(var + 1e-5f);
  const f32x4* g4 = (const f32x4*)lg;
  const f32x4* b4 = (const f32x4*)lb;
  f32x4 ga = g4[t], gb = g4[t+256], ba = b4[t], bb = b4[t+256];
  f32x4 ya, yb; u16x4 ha, hb;
#pragma unroll
  for (int i = 0; i < 4; ++i){
    ya[i] = (xa[i]-mean)*rstd*ga[i] + ba[i];
    yb[i] = (xb[i]-mean)*rstd*gb[i] + bb[i];
    ha[i] = f2bf(ya[i]); hb[i] = f2bf(yb[i]);
  }
  ((f32x4*)(xn32 + (size_t)s*DD))[t]     = ya;
  ((f32x4*)(xn32 + (size_t)s*DD))[t+256] = yb;
  ((u16x4*)(xn16 + (size_t)s*DD))[t]     = ha;
  ((u16x4*)(xn16 + (size_t)s*DD))[t+256] = hb;
}

// ---------------- K2: f32 -> bf16 convert (vectorized, grid-stride) ----------------
__global__ __launch_bounds__(256) void k_f32_to_bf16(
    const float* __restrict__ in, u16* __restrict__ out, int n4)
{
  int i = blockIdx.x * blockDim.x + threadIdx.x;
  const int stride = gridDim.x * blockDim.x;
  for (; i < n4; i += stride){
    f32x4 v = ((const f32x4*)in)[i];
    u16x4 h;
#pragma unroll
    for (int j = 0; j < 4; ++j) h[j] = f2bf(v[j]);
    ((u16x4*)out)[i] = h;
  }
}

// ---------------- shared 128x128 bf16 MFMA main loop (m97 structure) ----------------
// C[128,128] tile of A[M,K] @ B[N,K]^T ; 256 threads = 4 waves, each wave 64x64.
__device__ __forceinline__ void gemm_tile_128(
    const u16* A, const u16* B, int K, int bm, int bn,
    u16* lds_a, u16* lds_b, f32x4 acc[4][4])
{
  const int t = threadIdx.x;
  const int lane = t & 63;
  const int wm = (t >> 6) >> 1, wn = (t >> 6) & 1;
  const int g = lane >> 4, r16 = lane & 15;
  const u16* Ab = A + (size_t)bm * 128 * K;
  const u16* Bb = B + (size_t)bn * 128 * K;
  for (int kt = 0; kt < K; kt += 32){
#pragma unroll
    for (int half = 0; half < 2; ++half){
      const int tt = half*256 + t;
      const int row = tt >> 2, col = (tt & 3) * 8;
      gload_lds16(Ab + (size_t)row*K + kt + col, lds_a + tt*8);
      gload_lds16(Bb + (size_t)row*K + kt + col, lds_b + tt*8);
    }
    __syncthreads();
    bf16x8 af[4], bfr[4];
#pragma unroll
    for (int i = 0; i < 4; ++i){
      af[i]  = *(const bf16x8*)(lds_a + (wm*64 + i*16 + r16)*32 + g*8);
      bfr[i] = *(const bf16x8*)(lds_b + (wn*64 + i*16 + r16)*32 + g*8);
    }
#pragma unroll
    for (int a = 0; a < 4; ++a)
#pragma unroll
      for (int b = 0; b < 4; ++b)
        acc[a][b] = mfma16(af[a], bfr[b], acc[a][b]);
    __syncthreads();
  }
}

// ---------------- K3: QKV projection GEMM, scatter epilogue ----------------
__global__ __launch_bounds__(256) void k_gemm_qkv(
    const u16* __restrict__ A, const u16* __restrict__ B, const float* __restrict__ bias,
    u16* __restrict__ qws, u16* __restrict__ kws, u16* __restrict__ vtws)
{
  __shared__ __align__(16) u16 lds_a[128*32];
  __shared__ __align__(16) u16 lds_b[128*32];
  const int bm = blockIdx.x, bn = blockIdx.y;
  f32x4 acc[4][4] = {};
  gemm_tile_128(A, B, DD, bm, bn, lds_a, lds_b, acc);
  const int t = threadIdx.x, lane = t & 63;
  const int wm = (t >> 6) >> 1, wn = (t >> 6) & 1;
  const int g = lane >> 4, r16 = lane & 15;
  const int which = bn >> 4, h = bn & 15;
  const float qscale = 0.08838834764831845f; // 1/sqrt(128)
#pragma unroll
  for (int a = 0; a < 4; ++a){
#pragma unroll
    for (int b = 0; b < 4; ++b){
      const int hd = wn*64 + b*16 + r16;
      const float bi = bias[bn*128 + hd];
      const int s0 = bm*128 + wm*64 + a*16 + g*4;
      if (which == 0){
#pragma unroll
        for (int rr = 0; rr < 4; ++rr)
          qws[((size_t)h*SS + (s0+rr))*HDIM + hd] = f2bf((acc[a][b][rr] + bi) * qscale);
      } else if (which == 1){
#pragma unroll
        for (int rr = 0; rr < 4; ++rr)
          kws[((size_t)h*SS + (s0+rr))*HDIM + hd] = f2bf(acc[a][b][rr] + bi);
      } else {
        u16x4 pk;
#pragma unroll
        for (int rr = 0; rr < 4; ++rr) pk[rr] = f2bf(acc[a][b][rr] + bi);
        *(u16x4*)&vtws[((size_t)h*HDIM + hd)*SS + s0] = pk; // V^T: [H][hd][S]
      }
    }
  }
}

// ---------------- K4: flash attention (additive 0/1 segment mask) ----------------
__global__ __launch_bounds__(256) void k_attn(
    const u16* __restrict__ q, const u16* __restrict__ kk_, const u16* __restrict__ vt,
    const int* __restrict__ seg, u16* __restrict__ o)
{
  __shared__ __align__(16) u16 k_lds[64*136];    // [64][128+8] padded: kills D=128 bank conflict
  __shared__ __align__(16) u16 v_lds[128*72];    // V^T tile [128][64+8]
  __shared__ __align__(16) u16 p_lds[4][16*72];  // per-wave P [16][64+8]
  __shared__ int seg_lds[64];
  const int qb = blockIdx.x, h = blockIdx.y;
  const int t = threadIdx.x, lane = t & 63, w = t >> 6;
  const int g = lane >> 4, r16 = lane & 15;

  bf16x8 qf[4];
  {
    const u16* qp = q + ((size_t)h*SS + qb*64 + w*16 + r16) * HDIM;
#pragma unroll
    for (int c = 0; c < 4; ++c) qf[c] = *(const bf16x8*)(qp + c*32 + g*8);
  }
  int sq[4];
#pragma unroll
  for (int rr = 0; rr < 4; ++rr) sq[rr] = seg[qb*64 + w*16 + g*4 + rr];

  f32x4 oacc[8] = {};
  float mrun[4], lrun[4];
#pragma unroll
  for (int rr = 0; rr < 4; ++rr){ mrun[rr] = -1e30f; lrun[rr] = 0.f; }

  for (int kt = 0; kt < 32; ++kt){
    // stage K tile [64][128] and V^T tile [128][64] (padded LDS, reg-staged)
#pragma unroll
    for (int p4 = 0; p4 < 4; ++p4){
      const int tt = p4*256 + t;
      { const int row = tt >> 4, ch = tt & 15;
        *(bf16x8*)(k_lds + row*136 + ch*8) =
            *(const bf16x8*)(kk_ + ((size_t)h*SS + kt*64 + row)*HDIM + ch*8); }
      { const int row = tt >> 3, ch = tt & 7;
        *(bf16x8*)(v_lds + row*72 + ch*8) =
            *(const bf16x8*)(vt + ((size_t)h*HDIM + row)*SS + kt*64 + ch*8); }
    }
    if (t < 64) seg_lds[t] = seg[kt*64 + t];
    __syncthreads();

    // QK^T: per wave 16 q-rows x 64 keys
    f32x4 sacc[4] = {};
#pragma unroll
    for (int b = 0; b < 4; ++b)
#pragma unroll
      for (int c = 0; c < 4; ++c){
        bf16x8 kf = *(const bf16x8*)(k_lds + (b*16 + r16)*136 + c*32 + g*8);
        sacc[b] = mfma16(qf[c], kf, sacc[b]);
      }
    // additive mask
#pragma unroll
    for (int b = 0; b < 4; ++b){
      const int sk = seg_lds[b*16 + r16];
#pragma unroll
      for (int rr = 0; rr < 4; ++rr)
        sacc[b][rr] += (sk == sq[rr]) ? 1.0f : 0.0f;
    }
    // online softmax (row stats via 16-lane shfl_xor butterflies)
    float mx[4];
#pragma unroll
    for (int rr = 0; rr < 4; ++rr)
      mx[rr] = fmaxf(fmaxf(sacc[0][rr], sacc[1][rr]), fmaxf(sacc[2][rr], sacc[3][rr]));
#pragma unroll
    for (int off = 8; off > 0; off >>= 1)
#pragma unroll
      for (int rr = 0; rr < 4; ++rr)
        mx[rr] = fmaxf(mx[rr], __shfl_xor(mx[rr], off));
    float mnew[4], sc[4], ps[4];
#pragma unroll
    for (int rr = 0; rr < 4; ++rr){
      mnew[rr] = fmaxf(mrun[rr], mx[rr]);
      sc[rr] = __expf(mrun[rr] - mnew[rr]);
      ps[rr] = 0.f;
    }
#pragma unroll
    for (int b = 0; b < 4; ++b)
#pragma unroll
      for (int rr = 0; rr < 4; ++rr){
        const float pv = __expf(sacc[b][rr] - mnew[rr]);
        sacc[b][rr] = pv;
        ps[rr] += pv;
      }
#pragma unroll
    for (int off = 8; off > 0; off >>= 1)
#pragma unroll
      for (int rr = 0; rr < 4; ++rr)
        ps[rr] += __shfl_xor(ps[rr], off);
#pragma unroll
    for (int rr = 0; rr < 4; ++rr){
      lrun[rr] = lrun[rr]*sc[rr] + ps[rr];
      mrun[rr] = mnew[rr];
    }
#pragma unroll
    for (int f = 0; f < 8; ++f)
#pragma unroll
      for (int rr = 0; rr < 4; ++rr)
        oacc[f][rr] *= sc[rr];
    // P -> bf16 -> wave-private LDS (C-layout -> A-layout repack)
    u16* pw = p_lds[w];
#pragma unroll
    for (int b = 0; b < 4; ++b)
#pragma unroll
      for (int rr = 0; rr < 4; ++rr)
        pw[(g*4 + rr)*72 + b*16 + r16] = f2bf(sacc[b][rr]);
    __syncthreads();
    // PV: O[16][128] += P[16][64] @ V[64][128]
#pragma unroll
    for (int c = 0; c < 2; ++c){
      bf16x8 pa = *(const bf16x8*)(pw + r16*72 + c*32 + g*8);
#pragma unroll
      for (int f = 0; f < 8; ++f){
        bf16x8 vf = *(const bf16x8*)(v_lds + (f*16 + r16)*72 + c*32 + g*8);
        oacc[f] = mfma16(pa, vf, oacc[f]);
      }
    }
    __syncthreads();
  }
  // epilogue: divide by softmax denom, write o as bf16 [S][D]
#pragma unroll
  for (int f = 0; f < 8; ++f){
    const int hd = f*16 + r16;
#pragma unroll
    for (int rr = 0; rr < 4; ++rr){
      const int s = qb*64 + w*16 + g*4 + rr;
      o[(size_t)s*DD + h*HDIM + hd] = f2bf(oacc[f][rr] / lrun[rr]);
    }
  }
}

// ---------------- K5: output projection GEMM + bias + residual ----------------
__global__ __launch_bounds__(256) void k_gemm_out(
    const u16* __restrict__ A, const u16* __restrict__ B, const float* __restrict__ bias,
    const float* __restrict__ xn32, float* __restrict__ out)
{
  __shared__ __align__(16) u16 lds_a[128*32];
  __shared__ __align__(16) u16 lds_b[128*32];
  const int bm = blockIdx.x, bn = blockIdx.y;
  f32x4 acc[4][4] = {};
  gemm_tile_128(A, B, DD, bm, bn, lds_a, lds_b, acc);
  const int t = threadIdx.x, lane = t & 63;
  const int wm = (t >> 6) >> 1, wn = (t >> 6) & 1;
  const int g = lane >> 4, r16 = lane & 15;
#pragma unroll
  for (int a = 0; a < 4; ++a){
#pragma unroll
    for (int b = 0; b < 4; ++b){
      const int n = bn*128 + wn*64 + b*16 + r16;
      const float bi = bias[n];
#pragma unroll
      for (int rr = 0; rr < 4; ++rr){
        const int s = bm*128 + wm*64 + a*16 + g*4 + rr;
        out[(size_t)s*DD + n] = acc[a][b][rr] + bi + xn32[(size_t)s*DD + n];
      }
    }
  }
}

extern "C" void kernel_launch(void* const* d_in, const int* in_sizes, int n_in,
                              void* d_out, int out_size, void* d_ws, size_t ws_size,
                              hipStream_t stream)
{
  (void)in_sizes; (void)n_in; (void)out_size; (void)ws_size;
  const float* br     = (const float*)d_in[0];
  const int*   cat    = (const int*)d_in[1];
  const int*   cse    = (const int*)d_in[2];
  const int*   cmb    = (const int*)d_in[3];
  const int*   seg    = (const int*)d_in[4];
  const float* cat_e  = (const float*)d_in[5];
  const float* case_e = (const float*)d_in[6];
  const float* comb_e = (const float*)d_in[7];
  const float* ln_g   = (const float*)d_in[8];
  const float* ln_b   = (const float*)d_in[9];
  const float* in_w   = (const float*)d_in[10];
  const float* in_b   = (const float*)d_in[11];
  const float* out_w  = (const float*)d_in[12];
  const float* out_b  = (const float*)d_in[13];
  float* out = (float*)d_out;

  char* ws = (char*)d_ws;
  float* xn32  = (float*)(ws);                     // 16 MiB
  u16*   xn16  = (u16*)(ws + 16777216);            // 8 MiB
  u16*   inw16 = (u16*)(ws + 25165824);            // 24 MiB
  u16*   outw16= (u16*)(ws + 50331648);            // 8 MiB
  u16*   qws   = (u16*)(ws + 58720256);            // 8 MiB  [H][S][hd], pre-scaled
  u16*   kws   = (u16*)(ws + 67108864);            // 8 MiB  [H][S][hd]
  u16*   vtws  = (u16*)(ws + 75497472);            // 8 MiB  [H][hd][S]
  u16*   ows   = (u16*)(ws + 83886080);            // 8 MiB  [S][D]

  k_embed_ln<<<SS, 256, 0, stream>>>(br, cat, cse, cmb, cat_e, case_e, comb_e,
                                     ln_g, ln_b, xn32, xn16);
  k_f32_to_bf16<<<2048, 256, 0, stream>>>(in_w, inw16, 3*DD*DD/4);
  k_f32_to_bf16<<<2048, 256, 0, stream>>>(out_w, outw16, DD*DD/4);
  dim3 g1(16, 48);
  k_gemm_qkv<<<g1, 256, 0, stream>>>(xn16, inw16, in_b, qws, kws, vtws);
  dim3 g2(32, 16);
  k_attn<<<g2, 256, 0, stream>>>(qws, kws, vtws, seg, ows);
  dim3 g3(16, 16);
  k_gemm_out<<<g3, 256, 0, stream>>>(ows, outw16, out_b, xn32, out);
}